// Round 2
// baseline (664.442 us; speedup 1.0000x reference)
//
#include <hip/hip_runtime.h>
#include <hip/hip_bf16.h>
#include <math.h>

typedef __bf16 bf16;
typedef __attribute__((ext_vector_type(8))) bf16 bf16x8;
typedef __attribute__((ext_vector_type(2))) bf16 bf16x2;
typedef __attribute__((ext_vector_type(4))) float f32x4;

#define LOG2E 1.4426950408889634f
#define LOG2_THETA 18.931568569324174f   // log2(500000)

// ---- async global->LDS 16B copy (lane-scattered: lds_base + lane*16) ----
__device__ inline void async_cp16(const void* gptr, void* lptr) {
  __builtin_amdgcn_global_load_lds(
      (const __attribute__((address_space(1))) unsigned int*)gptr,
      (__attribute__((address_space(3))) unsigned int*)lptr, 16, 0, 0);
}

// ============================================================
// fp32 -> bf16 cast (n divisible by 2048; 8 elems/thread)
// ============================================================
__global__ __launch_bounds__(256) void cast_f32_bf16(
    const float* __restrict__ in, bf16* __restrict__ out, int n) {
  const int i = (blockIdx.x * 256 + threadIdx.x) * 8;
  if (i >= n) return;
  float4 a = *(const float4*)(in + i);
  float4 b = *(const float4*)(in + i + 4);
  bf16x8 o;
  o[0] = (bf16)a.x; o[1] = (bf16)a.y; o[2] = (bf16)a.z; o[3] = (bf16)a.w;
  o[4] = (bf16)b.x; o[5] = (bf16)b.y; o[6] = (bf16)b.z; o[7] = (bf16)b.w;
  *(bf16x8*)(out + i) = o;
}

// ============================================================
// GEMM: C[M,N] = A[M,K] @ W[N,K]^T + bias, optional clip(+-8)
// m97 structure: 128x128 tile, BK=32, 4 waves (2x2), 4x4 16x16 tiles/wave
// ============================================================
template <typename OUT_T, bool CLIP>
__global__ __launch_bounds__(256) void gemm_bt(
    const bf16* __restrict__ A, const bf16* __restrict__ W,
    const float* __restrict__ bias, OUT_T* __restrict__ C,
    int M, int N, int K) {
  __shared__ bf16 As[128 * 32];
  __shared__ bf16 Bs[128 * 32];
  const int m0 = blockIdx.x * 128, n0 = blockIdx.y * 128;
  const int t = threadIdx.x;
  const int w = t >> 6, lane = t & 63, quad = lane >> 4, l15 = lane & 15;
  const int wm = (w >> 1) * 64, wn = (w & 1) * 64;

  f32x4 acc[4][4];
#pragma unroll
  for (int i = 0; i < 4; i++)
#pragma unroll
    for (int j = 0; j < 4; j++) acc[i][j] = (f32x4)0.0f;

  const int rS = t >> 2;           // staging row (0..63) within half-tile
  const int cS = (t & 3) * 8;      // staging col (elements)

  for (int k0 = 0; k0 < K; k0 += 32) {
    async_cp16(A + (size_t)(m0 + rS) * K + k0 + cS, (char*)As + (size_t)(w * 64) * 16);
    async_cp16(A + (size_t)(m0 + 64 + rS) * K + k0 + cS, (char*)As + (size_t)(256 + w * 64) * 16);
    async_cp16(W + (size_t)(n0 + rS) * K + k0 + cS, (char*)Bs + (size_t)(w * 64) * 16);
    async_cp16(W + (size_t)(n0 + 64 + rS) * K + k0 + cS, (char*)Bs + (size_t)(256 + w * 64) * 16);
    __syncthreads();

    bf16x8 af[4], bfr[4];
#pragma unroll
    for (int i = 0; i < 4; i++)
      af[i] = *(const bf16x8*)(As + (wm + i * 16 + l15) * 32 + quad * 8);
#pragma unroll
    for (int j = 0; j < 4; j++)
      bfr[j] = *(const bf16x8*)(Bs + (wn + j * 16 + l15) * 32 + quad * 8);
#pragma unroll
    for (int i = 0; i < 4; i++)
#pragma unroll
      for (int j = 0; j < 4; j++)
        acc[i][j] = __builtin_amdgcn_mfma_f32_16x16x32_bf16(af[i], bfr[j], acc[i][j], 0, 0, 0);
    __syncthreads();
  }

#pragma unroll
  for (int i = 0; i < 4; i++)
#pragma unroll
    for (int j = 0; j < 4; j++) {
      const int col = n0 + wn + j * 16 + l15;
      const float bval = bias[col];
#pragma unroll
      for (int r = 0; r < 4; r++) {
        const int row = m0 + wm + i * 16 + quad * 4 + r;
        float v = acc[i][j][r] + bval;
        if (CLIP) v = fminf(fmaxf(v, -8.0f), 8.0f);
        C[(size_t)row * N + col] = (OUT_T)v;
      }
    }
}

// ============================================================
// LayerNorm + RoPE for q: rows of 2048 (bf16 in), out Q[b][h][t][d] bf16
// ============================================================
__global__ __launch_bounds__(256) void ln_rope_q(
    const bf16* __restrict__ X, const float* __restrict__ gamma,
    const float* __restrict__ beta, bf16* __restrict__ Q) {
  const int row = blockIdx.x;
  const int b = row >> 11, tpos = row & 2047;
  const bf16* x = X + (size_t)row * 2048;
  __shared__ float sh[2048];
  __shared__ float red[8];
  const int tid = threadIdx.x;
  const int w = tid >> 6, lane = tid & 63;

  bf16x8 xi = *(const bf16x8*)(x + tid * 8);
  float v[8];
  float s = 0.0f;
#pragma unroll
  for (int e = 0; e < 8; e++) { v[e] = (float)xi[e]; s += v[e]; }
#pragma unroll
  for (int m = 32; m >= 1; m >>= 1) s += __shfl_xor(s, m, 64);
  if (lane == 0) red[w] = s;
  __syncthreads();
  const float mean = (red[0] + red[1] + red[2] + red[3]) * (1.0f / 2048.0f);
  float vs = 0.0f;
#pragma unroll
  for (int e = 0; e < 8; e++) { float d = v[e] - mean; vs += d * d; }
#pragma unroll
  for (int m = 32; m >= 1; m >>= 1) vs += __shfl_xor(vs, m, 64);
  if (lane == 0) red[4 + w] = vs;
  __syncthreads();
  const float var = (red[4] + red[5] + red[6] + red[7]) * (1.0f / 2048.0f);
  const float rstd = rsqrtf(var + 1e-5f);
#pragma unroll
  for (int e = 0; e < 8; e++) {
    const int c = tid * 8 + e;
    const float y = (v[e] - mean) * rstd * gamma[c] + beta[c];
    sh[c] = y; v[e] = y;
  }
  __syncthreads();

  const int c0 = tid * 8;
  const int h = c0 >> 7;
  bf16x8 ov;
#pragma unroll
  for (int e = 0; e < 8; e++) {
    const int c = c0 + e, d = c & 127, i = d & 63;
    const float inv = exp2f((float)i * (-LOG2_THETA / 64.0f));
    float sn, cs;
    sincosf((float)tpos * inv, &sn, &cs);
    const float rot = (d < 64) ? -sh[c + 64] : sh[c - 64];
    ov[e] = (bf16)(v[e] * cs + rot * sn);
  }
  *(bf16x8*)(Q + ((size_t)(b * 16 + h) * 2048 + tpos) * 128 + (c0 & 127)) = ov;
}

// ============================================================
// LayerNorm + RoPE for k: rows of 512 (bf16 in), out K[b][kv][t][d] bf16
// ============================================================
__global__ __launch_bounds__(256) void ln_rope_k(
    const bf16* __restrict__ X, const float* __restrict__ gamma,
    const float* __restrict__ beta, bf16* __restrict__ Ko) {
  const int row = blockIdx.x;
  const int b = row >> 11, tpos = row & 2047;
  const bf16* x = X + (size_t)row * 512;
  __shared__ float sh[512];
  __shared__ float red[8];
  const int tid = threadIdx.x;
  const int w = tid >> 6, lane = tid & 63;

  bf16x2 xi = *(const bf16x2*)(x + tid * 2);
  float v0 = (float)xi[0], v1 = (float)xi[1];
  float s = v0 + v1;
#pragma unroll
  for (int m = 32; m >= 1; m >>= 1) s += __shfl_xor(s, m, 64);
  if (lane == 0) red[w] = s;
  __syncthreads();
  const float mean = (red[0] + red[1] + red[2] + red[3]) * (1.0f / 512.0f);
  float d0 = v0 - mean, d1 = v1 - mean;
  float vs = d0 * d0 + d1 * d1;
#pragma unroll
  for (int m = 32; m >= 1; m >>= 1) vs += __shfl_xor(vs, m, 64);
  if (lane == 0) red[4 + w] = vs;
  __syncthreads();
  const float var = (red[4] + red[5] + red[6] + red[7]) * (1.0f / 512.0f);
  const float rstd = rsqrtf(var + 1e-5f);
  const int c0 = tid * 2;
  float y0 = d0 * rstd * gamma[c0] + beta[c0];
  float y1 = d1 * rstd * gamma[c0 + 1] + beta[c0 + 1];
  sh[c0] = y0; sh[c0 + 1] = y1;
  __syncthreads();

  const int kv = c0 >> 7;
  float yy[2] = {y0, y1};
  bf16x2 ov;
#pragma unroll
  for (int e = 0; e < 2; e++) {
    const int c = c0 + e, d = c & 127, i = d & 63;
    const float inv = exp2f((float)i * (-LOG2_THETA / 64.0f));
    float sn, cs;
    sincosf((float)tpos * inv, &sn, &cs);
    const float rot = (d < 64) ? -sh[c + 64] : sh[c - 64];
    ov[e] = (bf16)(yy[e] * cs + rot * sn);
  }
  *(bf16x2*)(Ko + ((size_t)(b * 4 + kv) * 2048 + tpos) * 128 + (c0 & 127)) = ov;
}

// ============================================================
// V transpose: vb bf16[b*2048+t][kv*128+d] -> Vt[b][kv][d][t] bf16
// ============================================================
__global__ __launch_bounds__(256) void transpose_v(
    const bf16* __restrict__ V, bf16* __restrict__ Vt) {
  const int t0 = blockIdx.x * 64, kv = blockIdx.y, b = blockIdx.z;
  __shared__ bf16 tile[64][136];
  const int tid = threadIdx.x;
#pragma unroll
  for (int i = 0; i < 4; i++) {
    const int c = i * 256 + tid;             // [0,1024)
    const int r = c >> 4, d8 = (c & 15) * 8; // 64 rows x 128 cols
    *(bf16x8*)&tile[r][d8] =
        *(const bf16x8*)(V + (size_t)(b * 2048 + t0 + r) * 512 + kv * 128 + d8);
  }
  __syncthreads();
#pragma unroll
  for (int i = 0; i < 4; i++) {
    const int c = i * 256 + tid;
    const int d = c >> 3, t8 = (c & 7) * 8;
    bf16x8 o;
#pragma unroll
    for (int j = 0; j < 8; j++) o[j] = tile[t8 + j][d];
    *(bf16x8*)(Vt + (size_t)((b * 4 + kv) * 128 + d) * 2048 + t0 + t8) = o;
  }
}

// ============================================================
// Flash attention: block = (b, h, 64 q-rows); 4 waves x 16 rows; K-tile 64
// ============================================================
__global__ __launch_bounds__(256) void flash_attn(
    const bf16* __restrict__ Q, const bf16* __restrict__ Kt,
    const bf16* __restrict__ Vt, bf16* __restrict__ O) {
  const int qb = (int)gridDim.x - 1 - (int)blockIdx.x;  // heavy blocks first
  const int h = blockIdx.y, b = blockIdx.z;
  const int kv = h >> 2;
  const int q0 = qb * 64;
  const int tid = threadIdx.x;
  const int w = tid >> 6, lane = tid & 63, quad = lane >> 4, l15 = lane & 15;

  __shared__ bf16 Ks[64][152];   // K tile [key][d], padded
  __shared__ bf16 Vs[128][88];   // V^T tile [d][key], padded
  __shared__ bf16 Ps[4][16][88]; // per-wave P strip [qrow][key], padded

  const bf16* Qb = Q + ((size_t)(b * 16 + h) * 2048 + q0 + w * 16 + l15) * 128;
  bf16x8 aq[4];
#pragma unroll
  for (int kk = 0; kk < 4; kk++) aq[kk] = *(const bf16x8*)(Qb + kk * 32 + quad * 8);

  f32x4 o[8];
#pragma unroll
  for (int dt = 0; dt < 8; dt++) o[dt] = (f32x4)0.0f;
  float mi[4] = {-INFINITY, -INFINITY, -INFINITY, -INFINITY};
  float li[4] = {0.0f, 0.0f, 0.0f, 0.0f};
  const float cexp = 0.08838834764831845f * LOG2E;  // (1/sqrt(128)) * log2(e)

  const bf16* Kb = Kt + (size_t)(b * 4 + kv) * 2048 * 128;
  const bf16* Vb = Vt + (size_t)(b * 4 + kv) * 128 * 2048;

  const int nkt = qb + 1;
  for (int kt = 0; kt < nkt; kt++) {
    const int k0 = kt * 64;
#pragma unroll
    for (int i = 0; i < 4; i++) {  // K tile: 64x128
      const int c = i * 256 + tid;
      const int r = c >> 4, col8 = (c & 15) * 8;
      *(bf16x8*)&Ks[r][col8] = *(const bf16x8*)(Kb + (size_t)(k0 + r) * 128 + col8);
    }
#pragma unroll
    for (int i = 0; i < 4; i++) {  // Vt tile: 128x64
      const int c = i * 256 + tid;
      const int d = c >> 3, col8 = (c & 7) * 8;
      *(bf16x8*)&Vs[d][col8] = *(const bf16x8*)(Vb + (size_t)d * 2048 + k0 + col8);
    }
    __syncthreads();

    // S = Q K^T  (4 col tiles of 16 keys)
    f32x4 s[4];
#pragma unroll
    for (int j = 0; j < 4; j++) {
      f32x4 acc = (f32x4)0.0f;
#pragma unroll
      for (int kk = 0; kk < 4; kk++) {
        bf16x8 bk = *(const bf16x8*)&Ks[j * 16 + l15][kk * 32 + quad * 8];
        acc = __builtin_amdgcn_mfma_f32_16x16x32_bf16(aq[kk], bk, acc, 0, 0, 0);
      }
      s[j] = acc;
    }

    // causal mask + online softmax (row = q0 + w*16 + quad*4 + r)
    const int qrow_base = q0 + w * 16 + quad * 4;
#pragma unroll
    for (int r = 0; r < 4; r++) {
      float mx = -INFINITY;
#pragma unroll
      for (int j = 0; j < 4; j++) {
        const int kg = k0 + j * 16 + l15;
        if (kg > qrow_base + r) s[j][r] = -INFINITY;
        mx = fmaxf(mx, s[j][r]);
      }
#pragma unroll
      for (int msk = 8; msk >= 1; msk >>= 1) mx = fmaxf(mx, __shfl_xor(mx, msk, 64));
      const float mnew = fmaxf(mi[r], mx);
      const float alpha = exp2f((mi[r] - mnew) * cexp);
      mi[r] = mnew;
      li[r] *= alpha;
#pragma unroll
      for (int dt = 0; dt < 8; dt++) o[dt][r] *= alpha;
      float rs = 0.0f;
#pragma unroll
      for (int j = 0; j < 4; j++) {
        const float p = exp2f((s[j][r] - mnew) * cexp);
        s[j][r] = p; rs += p;
      }
#pragma unroll
      for (int msk = 8; msk >= 1; msk >>= 1) rs += __shfl_xor(rs, msk, 64);
      li[r] += rs;
    }

    // P -> LDS (wave-private strip), then PV
#pragma unroll
    for (int j = 0; j < 4; j++)
#pragma unroll
      for (int r = 0; r < 4; r++)
        Ps[w][quad * 4 + r][j * 16 + l15] = (bf16)s[j][r];
    __asm__ volatile("s_waitcnt lgkmcnt(0)" ::: "memory");

#pragma unroll
    for (int kk = 0; kk < 2; kk++) {
      bf16x8 pa = *(const bf16x8*)&Ps[w][l15][kk * 32 + quad * 8];
#pragma unroll
      for (int dt = 0; dt < 8; dt++) {
        bf16x8 vb = *(const bf16x8*)&Vs[dt * 16 + l15][kk * 32 + quad * 8];
        o[dt] = __builtin_amdgcn_mfma_f32_16x16x32_bf16(pa, vb, o[dt], 0, 0, 0);
      }
    }
    __syncthreads();
  }

  // epilogue: O /= l, write [b][t][h*128+d]
  bf16* Ob = O + ((size_t)(b * 2048 + q0 + w * 16 + quad * 4)) * 2048 + h * 128;
#pragma unroll
  for (int r = 0; r < 4; r++) {
    const float rinv = 1.0f / li[r];
#pragma unroll
    for (int dt = 0; dt < 8; dt++)
      Ob[(size_t)r * 2048 + dt * 16 + l15] = (bf16)(o[dt][r] * rinv);
  }
}

// ============================================================
// Launcher — fp32 inputs / fp32 output, bf16 compute internally.
// ws layout (bytes), total 88080384 (< 92.3MB proven available):
//   xb  bf16[4096x2048] : 0        .. 16777216   (reused as At after QKV gemms)
//   wqb bf16[2048x2048] : 16777216 .. 25165824
//   wkb bf16[ 512x2048] : 25165824 .. 27262976
//   wvb bf16[ 512x2048] : 27262976 .. 29360128
//   wob bf16[2048x2048] : 29360128 .. 37748736
//   qb  bf16[4096x2048] : 37748736 .. 54525952
//   kb  bf16[4096x 512] : 54525952 .. 58720256
//   vb  bf16[4096x 512] : 58720256 .. 62914560
//   Qr  bf16[2,16,2048,128] : 62914560 .. 79691776
//   Kr  bf16[2, 4,2048,128] : 79691776 .. 83886080
//   Vt  bf16[2, 4,128,2048] : 83886080 .. 88080384
// ============================================================
extern "C" void kernel_launch(void* const* d_in, const int* in_sizes, int n_in,
                              void* d_out, int out_size, void* d_ws, size_t ws_size,
                              hipStream_t stream) {
  const float* x   = (const float*)d_in[0];
  const float* wq  = (const float*)d_in[1];
  const float* bq  = (const float*)d_in[2];
  const float* wk  = (const float*)d_in[3];
  const float* bk  = (const float*)d_in[4];
  const float* wv  = (const float*)d_in[5];
  const float* bv  = (const float*)d_in[6];
  const float* wo  = (const float*)d_in[7];
  const float* bo  = (const float*)d_in[8];
  const float* qg  = (const float*)d_in[9];
  const float* qbt = (const float*)d_in[10];
  const float* kg  = (const float*)d_in[11];
  const float* kbt = (const float*)d_in[12];
  float* out = (float*)d_out;

  char* ws = (char*)d_ws;
  if (ws_size < (size_t)88080384) return;
  bf16* xb  = (bf16*)(ws);
  bf16* wqb = (bf16*)(ws + 16777216);
  bf16* wkb = (bf16*)(ws + 25165824);
  bf16* wvb = (bf16*)(ws + 27262976);
  bf16* wob = (bf16*)(ws + 29360128);
  bf16* qb  = (bf16*)(ws + 37748736);
  bf16* kb  = (bf16*)(ws + 54525952);
  bf16* vb  = (bf16*)(ws + 58720256);
  bf16* Qr  = (bf16*)(ws + 62914560);
  bf16* Kr  = (bf16*)(ws + 79691776);
  bf16* Vt  = (bf16*)(ws + 83886080);
  bf16* At  = (bf16*)(ws);  // aliases xb — x dead after QKV gemms

  cast_f32_bf16<<<4096, 256, 0, stream>>>(x,  xb,  8388608);
  cast_f32_bf16<<<2048, 256, 0, stream>>>(wq, wqb, 4194304);
  cast_f32_bf16<<<512,  256, 0, stream>>>(wk, wkb, 1048576);
  cast_f32_bf16<<<512,  256, 0, stream>>>(wv, wvb, 1048576);
  cast_f32_bf16<<<2048, 256, 0, stream>>>(wo, wob, 4194304);

  gemm_bt<bf16, true><<<dim3(32, 16), 256, 0, stream>>>(xb, wqb, bq, qb, 4096, 2048, 2048);
  gemm_bt<bf16, true><<<dim3(32, 4),  256, 0, stream>>>(xb, wkb, bk, kb, 4096, 512, 2048);
  gemm_bt<bf16, true><<<dim3(32, 4),  256, 0, stream>>>(xb, wvb, bv, vb, 4096, 512, 2048);
  ln_rope_q<<<4096, 256, 0, stream>>>(qb, qg, qbt, Qr);
  ln_rope_k<<<4096, 256, 0, stream>>>(kb, kg, kbt, Kr);
  transpose_v<<<dim3(32, 4, 2), 256, 0, stream>>>(vb, Vt);
  flash_attn<<<dim3(32, 16, 2), 256, 0, stream>>>(Qr, Kr, Vt, At);
  gemm_bt<float, false><<<dim3(32, 16), 256, 0, stream>>>(At, wob, bo, out, 4096, 2048, 2048);
}

// Round 3
// 352.499 us; speedup vs baseline: 1.8849x; 1.8849x over previous
//
#include <hip/hip_runtime.h>
#include <hip/hip_bf16.h>
#include <math.h>

typedef __bf16 bf16;
typedef __attribute__((ext_vector_type(8))) bf16 bf16x8;
typedef __attribute__((ext_vector_type(2))) bf16 bf16x2;
typedef __attribute__((ext_vector_type(4))) float f32x4;

#define LOG2E 1.4426950408889634f
#define LOG2_THETA 18.931568569324174f   // log2(500000)

#if __has_builtin(__builtin_amdgcn_exp2f)
#define EXP2F __builtin_amdgcn_exp2f
#else
#define EXP2F exp2f
#endif

// ---- async global->LDS 16B copy (lane-scattered: lds_base + lane*16) ----
__device__ inline void async_cp16(const void* gptr, void* lptr) {
  __builtin_amdgcn_global_load_lds(
      (const __attribute__((address_space(1))) unsigned int*)gptr,
      (__attribute__((address_space(3))) unsigned int*)lptr, 16, 0, 0);
}

// ============================================================
// fp32 -> bf16 cast (n divisible by 2048; 8 elems/thread)
// ============================================================
__global__ __launch_bounds__(256) void cast_f32_bf16(
    const float* __restrict__ in, bf16* __restrict__ out, int n) {
  const int i = (blockIdx.x * 256 + threadIdx.x) * 8;
  if (i >= n) return;
  float4 a = *(const float4*)(in + i);
  float4 b = *(const float4*)(in + i + 4);
  bf16x8 o;
  o[0] = (bf16)a.x; o[1] = (bf16)a.y; o[2] = (bf16)a.z; o[3] = (bf16)a.w;
  o[4] = (bf16)b.x; o[5] = (bf16)b.y; o[6] = (bf16)b.z; o[7] = (bf16)b.w;
  *(bf16x8*)(out + i) = o;
}

// ============================================================
// Fused QKV GEMM: C[M,3072] = A[M,2048] @ Wqkv[3072,2048]^T + bias, clip +-8
// cols 0..2047 = q (bq), 2048..2559 = k (bk), 2560..3071 = v (bv)
// ============================================================
__global__ __launch_bounds__(256) void gemm_qkv(
    const bf16* __restrict__ A, const bf16* __restrict__ W,
    const float* __restrict__ bq, const float* __restrict__ bk,
    const float* __restrict__ bv, bf16* __restrict__ C,
    int M, int N, int K) {
  __shared__ bf16 As[128 * 32];
  __shared__ bf16 Bs[128 * 32];
  const int m0 = blockIdx.x * 128, n0 = blockIdx.y * 128;
  const int t = threadIdx.x;
  const int w = t >> 6, lane = t & 63, quad = lane >> 4, l15 = lane & 15;
  const int wm = (w >> 1) * 64, wn = (w & 1) * 64;

  f32x4 acc[4][4];
#pragma unroll
  for (int i = 0; i < 4; i++)
#pragma unroll
    for (int j = 0; j < 4; j++) acc[i][j] = (f32x4)0.0f;

  const int rS = t >> 2;
  const int cS = (t & 3) * 8;

  for (int k0 = 0; k0 < K; k0 += 32) {
    async_cp16(A + (size_t)(m0 + rS) * K + k0 + cS, (char*)As + (size_t)(w * 64) * 16);
    async_cp16(A + (size_t)(m0 + 64 + rS) * K + k0 + cS, (char*)As + (size_t)(256 + w * 64) * 16);
    async_cp16(W + (size_t)(n0 + rS) * K + k0 + cS, (char*)Bs + (size_t)(w * 64) * 16);
    async_cp16(W + (size_t)(n0 + 64 + rS) * K + k0 + cS, (char*)Bs + (size_t)(256 + w * 64) * 16);
    __syncthreads();

    bf16x8 af[4], bfr[4];
#pragma unroll
    for (int i = 0; i < 4; i++)
      af[i] = *(const bf16x8*)(As + (wm + i * 16 + l15) * 32 + quad * 8);
#pragma unroll
    for (int j = 0; j < 4; j++)
      bfr[j] = *(const bf16x8*)(Bs + (wn + j * 16 + l15) * 32 + quad * 8);
#pragma unroll
    for (int i = 0; i < 4; i++)
#pragma unroll
      for (int j = 0; j < 4; j++)
        acc[i][j] = __builtin_amdgcn_mfma_f32_16x16x32_bf16(af[i], bfr[j], acc[i][j], 0, 0, 0);
    __syncthreads();
  }

#pragma unroll
  for (int i = 0; i < 4; i++)
#pragma unroll
    for (int j = 0; j < 4; j++) {
      const int col = n0 + wn + j * 16 + l15;
      float bval;
      if (col < 2048) bval = bq[col];
      else if (col < 2560) bval = bk[col - 2048];
      else bval = bv[col - 2560];
#pragma unroll
      for (int r = 0; r < 4; r++) {
        const int row = m0 + wm + i * 16 + quad * 4 + r;
        float v = acc[i][j][r] + bval;
        v = fminf(fmaxf(v, -8.0f), 8.0f);
        C[(size_t)row * N + col] = (bf16)v;
      }
    }
}

// ============================================================
// GEMM: C[M,N] = A[M,K] @ W[N,K]^T + bias (out-proj, fp32 out)
// ============================================================
template <typename OUT_T, bool CLIP>
__global__ __launch_bounds__(256) void gemm_bt(
    const bf16* __restrict__ A, const bf16* __restrict__ W,
    const float* __restrict__ bias, OUT_T* __restrict__ C,
    int M, int N, int K) {
  __shared__ bf16 As[128 * 32];
  __shared__ bf16 Bs[128 * 32];
  const int m0 = blockIdx.x * 128, n0 = blockIdx.y * 128;
  const int t = threadIdx.x;
  const int w = t >> 6, lane = t & 63, quad = lane >> 4, l15 = lane & 15;
  const int wm = (w >> 1) * 64, wn = (w & 1) * 64;

  f32x4 acc[4][4];
#pragma unroll
  for (int i = 0; i < 4; i++)
#pragma unroll
    for (int j = 0; j < 4; j++) acc[i][j] = (f32x4)0.0f;

  const int rS = t >> 2;
  const int cS = (t & 3) * 8;

  for (int k0 = 0; k0 < K; k0 += 32) {
    async_cp16(A + (size_t)(m0 + rS) * K + k0 + cS, (char*)As + (size_t)(w * 64) * 16);
    async_cp16(A + (size_t)(m0 + 64 + rS) * K + k0 + cS, (char*)As + (size_t)(256 + w * 64) * 16);
    async_cp16(W + (size_t)(n0 + rS) * K + k0 + cS, (char*)Bs + (size_t)(w * 64) * 16);
    async_cp16(W + (size_t)(n0 + 64 + rS) * K + k0 + cS, (char*)Bs + (size_t)(256 + w * 64) * 16);
    __syncthreads();

    bf16x8 af[4], bfr[4];
#pragma unroll
    for (int i = 0; i < 4; i++)
      af[i] = *(const bf16x8*)(As + (wm + i * 16 + l15) * 32 + quad * 8);
#pragma unroll
    for (int j = 0; j < 4; j++)
      bfr[j] = *(const bf16x8*)(Bs + (wn + j * 16 + l15) * 32 + quad * 8);
#pragma unroll
    for (int i = 0; i < 4; i++)
#pragma unroll
      for (int j = 0; j < 4; j++)
        acc[i][j] = __builtin_amdgcn_mfma_f32_16x16x32_bf16(af[i], bfr[j], acc[i][j], 0, 0, 0);
    __syncthreads();
  }

#pragma unroll
  for (int i = 0; i < 4; i++)
#pragma unroll
    for (int j = 0; j < 4; j++) {
      const int col = n0 + wn + j * 16 + l15;
      const float bval = bias[col];
#pragma unroll
      for (int r = 0; r < 4; r++) {
        const int row = m0 + wm + i * 16 + quad * 4 + r;
        float v = acc[i][j][r] + bval;
        if (CLIP) v = fminf(fmaxf(v, -8.0f), 8.0f);
        C[(size_t)row * N + col] = (OUT_T)v;
      }
    }
}

// ============================================================
// LayerNorm + RoPE for q: qkv rows (stride 3072, cols 0..2047) -> Q[b][h][t][d]
// ============================================================
__global__ __launch_bounds__(256) void ln_rope_q(
    const bf16* __restrict__ X, const float* __restrict__ gamma,
    const float* __restrict__ beta, bf16* __restrict__ Q) {
  const int row = blockIdx.x;
  const int b = row >> 11, tpos = row & 2047;
  const bf16* x = X + (size_t)row * 3072;
  __shared__ float sh[2048];
  __shared__ float red[8];
  const int tid = threadIdx.x;
  const int w = tid >> 6, lane = tid & 63;

  bf16x8 xi = *(const bf16x8*)(x + tid * 8);
  float v[8];
  float s = 0.0f;
#pragma unroll
  for (int e = 0; e < 8; e++) { v[e] = (float)xi[e]; s += v[e]; }
#pragma unroll
  for (int m = 32; m >= 1; m >>= 1) s += __shfl_xor(s, m, 64);
  if (lane == 0) red[w] = s;
  __syncthreads();
  const float mean = (red[0] + red[1] + red[2] + red[3]) * (1.0f / 2048.0f);
  float vs = 0.0f;
#pragma unroll
  for (int e = 0; e < 8; e++) { float d = v[e] - mean; vs += d * d; }
#pragma unroll
  for (int m = 32; m >= 1; m >>= 1) vs += __shfl_xor(vs, m, 64);
  if (lane == 0) red[4 + w] = vs;
  __syncthreads();
  const float var = (red[4] + red[5] + red[6] + red[7]) * (1.0f / 2048.0f);
  const float rstd = rsqrtf(var + 1e-5f);
#pragma unroll
  for (int e = 0; e < 8; e++) {
    const int c = tid * 8 + e;
    const float y = (v[e] - mean) * rstd * gamma[c] + beta[c];
    sh[c] = y; v[e] = y;
  }
  __syncthreads();

  const int c0 = tid * 8;
  const int h = c0 >> 7;
  bf16x8 ov;
#pragma unroll
  for (int e = 0; e < 8; e++) {
    const int c = c0 + e, d = c & 127, i = d & 63;
    const float inv = exp2f((float)i * (-LOG2_THETA / 64.0f));
    float sn, cs;
    sincosf((float)tpos * inv, &sn, &cs);
    const float rot = (d < 64) ? -sh[c + 64] : sh[c - 64];
    ov[e] = (bf16)(v[e] * cs + rot * sn);
  }
  *(bf16x8*)(Q + ((size_t)(b * 16 + h) * 2048 + tpos) * 128 + (c0 & 127)) = ov;
}

// ============================================================
// LayerNorm + RoPE for k: qkv rows (stride 3072, cols 2048..2559) -> K[b][kv][t][d]
// ============================================================
__global__ __launch_bounds__(256) void ln_rope_k(
    const bf16* __restrict__ X, const float* __restrict__ gamma,
    const float* __restrict__ beta, bf16* __restrict__ Ko) {
  const int row = blockIdx.x;
  const int b = row >> 11, tpos = row & 2047;
  const bf16* x = X + (size_t)row * 3072 + 2048;
  __shared__ float sh[512];
  __shared__ float red[8];
  const int tid = threadIdx.x;
  const int w = tid >> 6, lane = tid & 63;

  bf16x2 xi = *(const bf16x2*)(x + tid * 2);
  float v0 = (float)xi[0], v1 = (float)xi[1];
  float s = v0 + v1;
#pragma unroll
  for (int m = 32; m >= 1; m >>= 1) s += __shfl_xor(s, m, 64);
  if (lane == 0) red[w] = s;
  __syncthreads();
  const float mean = (red[0] + red[1] + red[2] + red[3]) * (1.0f / 512.0f);
  float d0 = v0 - mean, d1 = v1 - mean;
  float vs = d0 * d0 + d1 * d1;
#pragma unroll
  for (int m = 32; m >= 1; m >>= 1) vs += __shfl_xor(vs, m, 64);
  if (lane == 0) red[4 + w] = vs;
  __syncthreads();
  const float var = (red[4] + red[5] + red[6] + red[7]) * (1.0f / 512.0f);
  const float rstd = rsqrtf(var + 1e-5f);
  const int c0 = tid * 2;
  float y0 = d0 * rstd * gamma[c0] + beta[c0];
  float y1 = d1 * rstd * gamma[c0 + 1] + beta[c0 + 1];
  sh[c0] = y0; sh[c0 + 1] = y1;
  __syncthreads();

  const int kv = c0 >> 7;
  float yy[2] = {y0, y1};
  bf16x2 ov;
#pragma unroll
  for (int e = 0; e < 2; e++) {
    const int c = c0 + e, d = c & 127, i = d & 63;
    const float inv = exp2f((float)i * (-LOG2_THETA / 64.0f));
    float sn, cs;
    sincosf((float)tpos * inv, &sn, &cs);
    const float rot = (d < 64) ? -sh[c + 64] : sh[c - 64];
    ov[e] = (bf16)(yy[e] * cs + rot * sn);
  }
  *(bf16x2*)(Ko + ((size_t)(b * 4 + kv) * 2048 + tpos) * 128 + (c0 & 127)) = ov;
}

// ============================================================
// V transpose: qkv[row][2560 + kv*128 + d] (stride 3072) -> Vt[b][kv][d][t]
// ============================================================
__global__ __launch_bounds__(256) void transpose_v(
    const bf16* __restrict__ V, bf16* __restrict__ Vt) {
  const int t0 = blockIdx.x * 64, kv = blockIdx.y, b = blockIdx.z;
  __shared__ bf16 tile[64][136];
  const int tid = threadIdx.x;
#pragma unroll
  for (int i = 0; i < 4; i++) {
    const int c = i * 256 + tid;
    const int r = c >> 4, d8 = (c & 15) * 8;
    *(bf16x8*)&tile[r][d8] =
        *(const bf16x8*)(V + (size_t)(b * 2048 + t0 + r) * 3072 + 2560 + kv * 128 + d8);
  }
  __syncthreads();
#pragma unroll
  for (int i = 0; i < 4; i++) {
    const int c = i * 256 + tid;
    const int d = c >> 3, t8 = (c & 7) * 8;
    bf16x8 o;
#pragma unroll
    for (int j = 0; j < 8; j++) o[j] = tile[t8 + j][d];
    *(bf16x8*)(Vt + (size_t)((b * 4 + kv) * 128 + d) * 2048 + t0 + t8) = o;
  }
}

// ============================================================
// Flash attention, v2:
//  - grid (16,16,2); block p does q-tiles {31-p, p} -> uniform 33 k-tiles
//  - fixed-max softmax (no running max, no cross-lane reductions)
//  - denominator via PV MFMA with constant all-ones B fragment
//  - async swizzled global->LDS staging, single 64-key K/V buffer
// LDS: Ks 16K + Vs 16K + Ps 11K = 44K -> fits 64K cap, 2 blocks/CU by grid
// ============================================================
__global__ __launch_bounds__(256) void flash_attn(
    const bf16* __restrict__ Q, const bf16* __restrict__ Kt,
    const bf16* __restrict__ Vt, bf16* __restrict__ O) {
  const int p = blockIdx.x;            // 0..15
  const int h = blockIdx.y, b = blockIdx.z;
  const int kv = h >> 2;
  const int tid = threadIdx.x;
  const int w = tid >> 6, lane = tid & 63, quad = lane >> 4, l15 = lane & 15;

  __shared__ bf16 Ks[64][128];   // [key][d], XOR-swizzled 16B segs within row
  __shared__ bf16 Vs[128][64];   // [d][key], XOR-swizzled 16B segs within row
  __shared__ bf16 Ps[4][16][88]; // per-wave P strip [qrow][key], padded

  const bf16* Kb = Kt + (size_t)(b * 4 + kv) * 2048 * 128;
  const bf16* Vb = Vt + (size_t)(b * 4 + kv) * 128 * 2048;

  // per-lane swizzled staging offsets (elements), computed once
  const int ksl = lane & 15, krt = lane >> 4;   // K chunk: 4 rows x 16 segs
  const int vsl = lane & 7,  vdt = lane >> 3;   // V chunk: 8 rows x 8 segs
  int okff[4], ovff[4];
#pragma unroll
  for (int i = 0; i < 4; i++) {
    const int c = w * 4 + i;
    const int rt = c * 4 + krt;
    okff[i] = rt * 128 + ((ksl ^ (rt & 15)) * 8);
    const int d = c * 8 + vdt;
    ovff[i] = d * 2048 + ((vsl ^ (d & 7)) * 8);
  }

  const float cexp = 0.08838834764831845f * LOG2E;  // scale * log2(e)
  bf16x8 ones;
#pragma unroll
  for (int i = 0; i < 8; i++) ones[i] = (bf16)1.0f;

#pragma unroll 1
  for (int pass = 0; pass < 2; pass++) {
    const int qb = (pass == 0) ? (31 - p) : p;
    const int q0 = qb * 64;
    const int nkt = qb + 1;

    const bf16* Qb = Q + ((size_t)(b * 16 + h) * 2048 + q0 + w * 16 + l15) * 128;
    bf16x8 aq[4];
#pragma unroll
    for (int kk = 0; kk < 4; kk++) aq[kk] = *(const bf16x8*)(Qb + kk * 32 + quad * 8);

    f32x4 o[9];   // o[8] accumulates the softmax denominator (P @ ones)
#pragma unroll
    for (int dt = 0; dt < 9; dt++) o[dt] = (f32x4)0.0f;

#pragma unroll 1
    for (int kt = 0; kt < nkt; kt++) {
      const int k0 = kt * 64;
      __syncthreads();  // prev compute done everywhere; buffer reusable
      // stage K/V tile kt (async DMA; drained by next barrier's vmcnt(0))
      {
        const size_t kbase = (size_t)k0 * 128;
#pragma unroll
        for (int i = 0; i < 4; i++) {
          const int c = w * 4 + i;
          async_cp16(Kb + kbase + okff[i], (char*)&Ks[0][0] + c * 1024);
          async_cp16(Vb + (size_t)k0 + ovff[i], (char*)&Vs[0][0] + c * 1024);
        }
      }
      __syncthreads();  // compiler inserts vmcnt(0): all staging landed

      // S = Q K^T  (4 col tiles of 16 keys)
      f32x4 s4[4];
#pragma unroll
      for (int j = 0; j < 4; j++) {
        f32x4 acc = (f32x4)0.0f;
        const int n = j * 16 + l15;
#pragma unroll
        for (int kk = 0; kk < 4; kk++) {
          bf16x8 bk = *(const bf16x8*)(
              &Ks[0][0] + n * 128 + (((kk * 4 + quad) ^ l15) * 8));
          acc = __builtin_amdgcn_mfma_f32_16x16x32_bf16(aq[kk], bk, acc, 0, 0, 0);
        }
        s4[j] = acc;
      }

      // fixed-max softmax: p = exp2(s*c), masked -> 0. No cross-lane ops.
      const bool diag = (kt == qb);
      const int qrow_base = q0 + w * 16 + quad * 4;
#pragma unroll
      for (int j = 0; j < 4; j++) {
        const int kg = k0 + j * 16 + l15;
#pragma unroll
        for (int r = 0; r < 4; r++) {
          float pv = EXP2F(s4[j][r] * cexp);
          if (diag && kg > qrow_base + r) pv = 0.0f;
          Ps[w][quad * 4 + r][j * 16 + l15] = (bf16)pv;
        }
      }
      __asm__ volatile("s_waitcnt lgkmcnt(0)" ::: "memory");

      // O += P V ; o[8] += P @ ones (denominator)
#pragma unroll
      for (int kk = 0; kk < 2; kk++) {
        bf16x8 pa = *(const bf16x8*)&Ps[w][l15][kk * 32 + quad * 8];
#pragma unroll
        for (int dt = 0; dt < 8; dt++) {
          const int d = dt * 16 + l15;
          bf16x8 vb = *(const bf16x8*)(
              &Vs[0][0] + d * 64 + (((kk * 4 + quad) ^ (d & 7)) * 8));
          o[dt] = __builtin_amdgcn_mfma_f32_16x16x32_bf16(pa, vb, o[dt], 0, 0, 0);
        }
        o[8] = __builtin_amdgcn_mfma_f32_16x16x32_bf16(pa, ones, o[8], 0, 0, 0);
      }
    }

    // epilogue: O /= l, write [b][t][h*128+d]
    bf16* Ob = O + ((size_t)(b * 2048 + q0 + w * 16 + quad * 4)) * 2048 + h * 128;
#pragma unroll
    for (int r = 0; r < 4; r++) {
      const float rinv = 1.0f / o[8][r];
#pragma unroll
      for (int dt = 0; dt < 8; dt++)
        Ob[(size_t)r * 2048 + dt * 16 + l15] = (bf16)(o[dt][r] * rinv);
    }
  }
}

// ============================================================
// Launcher — fp32 in/out, bf16 compute.
// ws layout (bytes), total 88080384:
//   xb    bf16[4096x2048] : 0        .. 16777216  (reused as At)
//   wqkvb bf16[3072x2048] : 16777216 .. 29360128
//   wob   bf16[2048x2048] : 29360128 .. 37748736
//   qkvb  bf16[4096x3072] : 37748736 .. 62914560
//   Qr    bf16[2,16,2048,128] : 62914560 .. 79691776
//   Kr    bf16[2, 4,2048,128] : 79691776 .. 83886080
//   Vt    bf16[2, 4,128,2048] : 83886080 .. 88080384
// ============================================================
extern "C" void kernel_launch(void* const* d_in, const int* in_sizes, int n_in,
                              void* d_out, int out_size, void* d_ws, size_t ws_size,
                              hipStream_t stream) {
  const float* x   = (const float*)d_in[0];
  const float* wq  = (const float*)d_in[1];
  const float* bq  = (const float*)d_in[2];
  const float* wk  = (const float*)d_in[3];
  const float* bk  = (const float*)d_in[4];
  const float* wv  = (const float*)d_in[5];
  const float* bv  = (const float*)d_in[6];
  const float* wo  = (const float*)d_in[7];
  const float* bo  = (const float*)d_in[8];
  const float* qg  = (const float*)d_in[9];
  const float* qbt = (const float*)d_in[10];
  const float* kg  = (const float*)d_in[11];
  const float* kbt = (const float*)d_in[12];
  float* out = (float*)d_out;

  char* ws = (char*)d_ws;
  if (ws_size < (size_t)88080384) return;
  bf16* xb    = (bf16*)(ws);
  bf16* wqkvb = (bf16*)(ws + 16777216);
  bf16* wob   = (bf16*)(ws + 29360128);
  bf16* qkvb  = (bf16*)(ws + 37748736);
  bf16* Qr    = (bf16*)(ws + 62914560);
  bf16* Kr    = (bf16*)(ws + 79691776);
  bf16* Vt    = (bf16*)(ws + 83886080);
  bf16* At    = (bf16*)(ws);  // aliases xb — x dead after QKV gemm

  cast_f32_bf16<<<4096, 256, 0, stream>>>(x,  xb, 8388608);
  cast_f32_bf16<<<2048, 256, 0, stream>>>(wq, wqkvb, 4194304);
  cast_f32_bf16<<<512,  256, 0, stream>>>(wk, wqkvb + (size_t)2048 * 2048, 1048576);
  cast_f32_bf16<<<512,  256, 0, stream>>>(wv, wqkvb + (size_t)2560 * 2048, 1048576);
  cast_f32_bf16<<<2048, 256, 0, stream>>>(wo, wob, 4194304);

  gemm_qkv<<<dim3(32, 24), 256, 0, stream>>>(xb, wqkvb, bq, bk, bv, qkvb, 4096, 3072, 2048);
  ln_rope_q<<<4096, 256, 0, stream>>>(qkvb, qg, qbt, Qr);
  ln_rope_k<<<4096, 256, 0, stream>>>(qkvb, kg, kbt, Kr);
  transpose_v<<<dim3(32, 4, 2), 256, 0, stream>>>(qkvb, Vt);
  flash_attn<<<dim3(16, 16, 2), 256, 0, stream>>>(Qr, Kr, Vt, At);
  gemm_bt<float, false><<<dim3(32, 16), 256, 0, stream>>>(At, wob, bo, out, 4096, 2048, 2048);
}

// Round 4
// 329.778 us; speedup vs baseline: 2.0148x; 1.0689x over previous
//
#include <hip/hip_runtime.h>
#include <hip/hip_bf16.h>
#include <math.h>

typedef __bf16 bf16;
typedef __attribute__((ext_vector_type(8))) bf16 bf16x8;
typedef __attribute__((ext_vector_type(2))) bf16 bf16x2;
typedef __attribute__((ext_vector_type(4))) float f32x4;

#define LOG2E 1.4426950408889634f
#define LOG2_THETA 18.931568569324174f   // log2(500000)

#if __has_builtin(__builtin_amdgcn_exp2f)
#define EXP2F __builtin_amdgcn_exp2f
#else
#define EXP2F exp2f
#endif

// ---- async global->LDS 16B copy (lane-scattered: lds_base + lane*16) ----
__device__ inline void async_cp16(const void* gptr, void* lptr) {
  __builtin_amdgcn_global_load_lds(
      (const __attribute__((address_space(1))) unsigned int*)gptr,
      (__attribute__((address_space(3))) unsigned int*)lptr, 16, 0, 0);
}

// ============================================================
// Fused fp32->bf16 cast of x, wq|wk|wv (contiguous dst), wo.
// 9216 blocks x 256 thr x 8 elems = 18874368 elems total.
// ============================================================
__global__ __launch_bounds__(256) void cast_all(
    const float* __restrict__ x,  const float* __restrict__ wq,
    const float* __restrict__ wk, const float* __restrict__ wv,
    const float* __restrict__ wo, bf16* __restrict__ xb,
    bf16* __restrict__ wqkvb, bf16* __restrict__ wob) {
  const int bx = blockIdx.x;
  const size_t gi = ((size_t)bx * 256 + threadIdx.x) * 8;
  const float* src;
  bf16* dst;
  if (bx < 4096)      { src = x  + gi;              dst = xb + gi; }
  else if (bx < 6144) { src = wq + (gi -  8388608); dst = wqkvb + (gi - 8388608); }
  else if (bx < 6656) { src = wk + (gi - 12582912); dst = wqkvb + 4194304 + (gi - 12582912); }
  else if (bx < 7168) { src = wv + (gi - 13631488); dst = wqkvb + 5242880 + (gi - 13631488); }
  else                { src = wo + (gi - 14680064); dst = wob + (gi - 14680064); }
  float4 a = *(const float4*)(src);
  float4 b = *(const float4*)(src + 4);
  bf16x8 o;
  o[0] = (bf16)a.x; o[1] = (bf16)a.y; o[2] = (bf16)a.z; o[3] = (bf16)a.w;
  o[4] = (bf16)b.x; o[5] = (bf16)b.y; o[6] = (bf16)b.z; o[7] = (bf16)b.w;
  *(bf16x8*)dst = o;
}

// ============================================================
// GEMM core: C[M,N] = A[M,K] @ W[N,K]^T, 128x128 tile, BK=64,
// XOR-swizzled LDS (16B seg s at phys s^(row&7)), async staging.
// QKV variant: 3-way bias + clip; plain variant: bias only.
// ============================================================
template <typename OUT_T, bool QKV, bool CLIP>
__global__ __launch_bounds__(256) void gemm_bt(
    const bf16* __restrict__ A, const bf16* __restrict__ W,
    const float* __restrict__ b0, const float* __restrict__ b1,
    const float* __restrict__ b2, OUT_T* __restrict__ C,
    int M, int N, int K) {
  __shared__ bf16 As[128 * 64];   // 16 KB, swizzled
  __shared__ bf16 Bs[128 * 64];
  const int m0 = blockIdx.x * 128, n0 = blockIdx.y * 128;
  const int t = threadIdx.x;
  const int w = t >> 6, lane = t & 63, quad = lane >> 4, l15 = lane & 15;
  const int sw = l15 & 7;
  const int wm = (w >> 1) * 64, wn = (w & 1) * 64;

  f32x4 acc[4][4];
#pragma unroll
  for (int i = 0; i < 4; i++)
#pragma unroll
    for (int j = 0; j < 4; j++) acc[i][j] = (f32x4)0.0f;

  // staging: 1024 16B chunks per tile; chunk c -> row=c>>3, phys seg=c&7,
  // logical seg = (c&7)^(row&7). 4 chunks/thread per matrix.
  int soff[4];
#pragma unroll
  for (int i = 0; i < 4; i++) {
    const int c = w * 256 + i * 64 + lane;
    const int r = c >> 3;
    const int sl = (c & 7) ^ (r & 7);
    soff[i] = r * K + sl * 8;
  }
  const bf16* Abase = A + (size_t)m0 * K;
  const bf16* Wbase = W + (size_t)n0 * K;

  for (int k0 = 0; k0 < K; k0 += 64) {
#pragma unroll
    for (int i = 0; i < 4; i++) {
      const int dst = (w * 256 + i * 64) * 16;
      async_cp16(Abase + k0 + soff[i], (char*)As + dst);
      async_cp16(Wbase + k0 + soff[i], (char*)Bs + dst);
    }
    __syncthreads();  // (waits staging of THIS tile via compiler vmcnt(0))

#pragma unroll
    for (int kk = 0; kk < 2; kk++) {
      bf16x8 af[4], bfr[4];
#pragma unroll
      for (int i = 0; i < 4; i++)
        af[i] = *(const bf16x8*)(As + (wm + i * 16 + l15) * 64 +
                                 (((kk * 4 + quad) ^ sw) * 8));
#pragma unroll
      for (int j = 0; j < 4; j++)
        bfr[j] = *(const bf16x8*)(Bs + (wn + j * 16 + l15) * 64 +
                                  (((kk * 4 + quad) ^ sw) * 8));
#pragma unroll
      for (int i = 0; i < 4; i++)
#pragma unroll
        for (int j = 0; j < 4; j++)
          acc[i][j] = __builtin_amdgcn_mfma_f32_16x16x32_bf16(af[i], bfr[j], acc[i][j], 0, 0, 0);
    }
    __syncthreads();
  }

#pragma unroll
  for (int i = 0; i < 4; i++)
#pragma unroll
    for (int j = 0; j < 4; j++) {
      const int col = n0 + wn + j * 16 + l15;
      float bval;
      if (QKV) {
        if (col < 2048) bval = b0[col];
        else if (col < 2560) bval = b1[col - 2048];
        else bval = b2[col - 2560];
      } else {
        bval = b0[col];
      }
#pragma unroll
      for (int r = 0; r < 4; r++) {
        const int row = m0 + wm + i * 16 + quad * 4 + r;
        float v = acc[i][j][r] + bval;
        if (CLIP) v = fminf(fmaxf(v, -8.0f), 8.0f);
        C[(size_t)row * N + col] = (OUT_T)v;
      }
    }
}

// ============================================================
// Fused mid stage: role by blockIdx.x
//   [0,4096)    : LN+RoPE q  (qkv row, cols 0..2047)  -> Qr[b][h][t][d]
//   [4096,8192) : LN+RoPE k  (cols 2048..2559)        -> Kr[b][kv][t][d]
//   [8192,8448) : V transpose (cols 2560..3071)       -> Vt[b][kv][d][t]
// ============================================================
__global__ __launch_bounds__(256) void fused_mid(
    const bf16* __restrict__ X, const float* __restrict__ qg,
    const float* __restrict__ qb, const float* __restrict__ kg,
    const float* __restrict__ kb, bf16* __restrict__ Qr,
    bf16* __restrict__ Kr, bf16* __restrict__ Vt) {
  __shared__ float smf[2056];
  __shared__ bf16 smt[64][136];
  const int bx = blockIdx.x;
  const int tid = threadIdx.x;
  const int w = tid >> 6, lane = tid & 63;
  float* red = smf + 2048;

  if (bx < 4096) {
    // ---- LN + RoPE q ----
    const int row = bx, b = row >> 11, tpos = row & 2047;
    const bf16* x = X + (size_t)row * 3072;
    bf16x8 xi = *(const bf16x8*)(x + tid * 8);
    float v[8];
    float s = 0.0f;
#pragma unroll
    for (int e = 0; e < 8; e++) { v[e] = (float)xi[e]; s += v[e]; }
#pragma unroll
    for (int m = 32; m >= 1; m >>= 1) s += __shfl_xor(s, m, 64);
    if (lane == 0) red[w] = s;
    __syncthreads();
    const float mean = (red[0] + red[1] + red[2] + red[3]) * (1.0f / 2048.0f);
    float vs = 0.0f;
#pragma unroll
    for (int e = 0; e < 8; e++) { float d = v[e] - mean; vs += d * d; }
#pragma unroll
    for (int m = 32; m >= 1; m >>= 1) vs += __shfl_xor(vs, m, 64);
    if (lane == 0) red[4 + w] = vs;
    __syncthreads();
    const float var = (red[4] + red[5] + red[6] + red[7]) * (1.0f / 2048.0f);
    const float rstd = rsqrtf(var + 1e-5f);
#pragma unroll
    for (int e = 0; e < 8; e++) {
      const int c = tid * 8 + e;
      const float y = (v[e] - mean) * rstd * qg[c] + qb[c];
      smf[c] = y; v[e] = y;
    }
    __syncthreads();
    const int c0 = tid * 8;
    const int h = c0 >> 7;
    bf16x8 ov;
#pragma unroll
    for (int e = 0; e < 8; e++) {
      const int c = c0 + e, d = c & 127, i = d & 63;
      const float inv = exp2f((float)i * (-LOG2_THETA / 64.0f));
      float sn, cs;
      sincosf((float)tpos * inv, &sn, &cs);
      const float rot = (d < 64) ? -smf[c + 64] : smf[c - 64];
      ov[e] = (bf16)(v[e] * cs + rot * sn);
    }
    *(bf16x8*)(Qr + ((size_t)(b * 16 + h) * 2048 + tpos) * 128 + (c0 & 127)) = ov;
  } else if (bx < 8192) {
    // ---- LN + RoPE k ----
    const int row = bx - 4096, b = row >> 11, tpos = row & 2047;
    const bf16* x = X + (size_t)row * 3072 + 2048;
    bf16x2 xi = *(const bf16x2*)(x + tid * 2);
    float v0 = (float)xi[0], v1 = (float)xi[1];
    float s = v0 + v1;
#pragma unroll
    for (int m = 32; m >= 1; m >>= 1) s += __shfl_xor(s, m, 64);
    if (lane == 0) red[w] = s;
    __syncthreads();
    const float mean = (red[0] + red[1] + red[2] + red[3]) * (1.0f / 512.0f);
    float d0 = v0 - mean, d1 = v1 - mean;
    float vs = d0 * d0 + d1 * d1;
#pragma unroll
    for (int m = 32; m >= 1; m >>= 1) vs += __shfl_xor(vs, m, 64);
    if (lane == 0) red[4 + w] = vs;
    __syncthreads();
    const float var = (red[4] + red[5] + red[6] + red[7]) * (1.0f / 512.0f);
    const float rstd = rsqrtf(var + 1e-5f);
    const int c0 = tid * 2;
    float y0 = d0 * rstd * kg[c0] + kb[c0];
    float y1 = d1 * rstd * kg[c0 + 1] + kb[c0 + 1];
    smf[c0] = y0; smf[c0 + 1] = y1;
    __syncthreads();
    const int kv = c0 >> 7;
    float yy[2] = {y0, y1};
    bf16x2 ov;
#pragma unroll
    for (int e = 0; e < 2; e++) {
      const int c = c0 + e, d = c & 127, i = d & 63;
      const float inv = exp2f((float)i * (-LOG2_THETA / 64.0f));
      float sn, cs;
      sincosf((float)tpos * inv, &sn, &cs);
      const float rot = (d < 64) ? -smf[c + 64] : smf[c - 64];
      ov[e] = (bf16)(yy[e] * cs + rot * sn);
    }
    *(bf16x2*)(Kr + ((size_t)(b * 4 + kv) * 2048 + tpos) * 128 + (c0 & 127)) = ov;
  } else {
    // ---- V transpose ----
    const int idx = bx - 8192;
    const int b = idx >> 7, kv = (idx >> 5) & 3, t0 = (idx & 31) * 64;
#pragma unroll
    for (int i = 0; i < 4; i++) {
      const int c = i * 256 + tid;
      const int r = c >> 4, d8 = (c & 15) * 8;
      *(bf16x8*)&smt[r][d8] =
          *(const bf16x8*)(X + (size_t)(b * 2048 + t0 + r) * 3072 + 2560 + kv * 128 + d8);
    }
    __syncthreads();
#pragma unroll
    for (int i = 0; i < 4; i++) {
      const int c = i * 256 + tid;
      const int d = c >> 3, t8 = (c & 7) * 8;
      bf16x8 o;
#pragma unroll
      for (int j = 0; j < 8; j++) o[j] = smt[t8 + j][d];
      *(bf16x8*)(Vt + (size_t)((b * 4 + kv) * 128 + d) * 2048 + t0 + t8) = o;
    }
  }
}

// ============================================================
// Flash attention (unchanged from R3):
//  - grid (16,16,2); block p does q-tiles {31-p, p} -> uniform 33 k-tiles
//  - fixed-max softmax, denominator via PV MFMA with all-ones B
//  - async swizzled global->LDS staging, single 64-key K/V buffer
// ============================================================
__global__ __launch_bounds__(256) void flash_attn(
    const bf16* __restrict__ Q, const bf16* __restrict__ Kt,
    const bf16* __restrict__ Vt, bf16* __restrict__ O) {
  const int p = blockIdx.x;
  const int h = blockIdx.y, b = blockIdx.z;
  const int kv = h >> 2;
  const int tid = threadIdx.x;
  const int w = tid >> 6, lane = tid & 63, quad = lane >> 4, l15 = lane & 15;

  __shared__ bf16 Ks[64][128];
  __shared__ bf16 Vs[128][64];
  __shared__ bf16 Ps[4][16][88];

  const bf16* Kb = Kt + (size_t)(b * 4 + kv) * 2048 * 128;
  const bf16* Vb = Vt + (size_t)(b * 4 + kv) * 128 * 2048;

  const int ksl = lane & 15, krt = lane >> 4;
  const int vsl = lane & 7,  vdt = lane >> 3;
  int okff[4], ovff[4];
#pragma unroll
  for (int i = 0; i < 4; i++) {
    const int c = w * 4 + i;
    const int rt = c * 4 + krt;
    okff[i] = rt * 128 + ((ksl ^ (rt & 15)) * 8);
    const int d = c * 8 + vdt;
    ovff[i] = d * 2048 + ((vsl ^ (d & 7)) * 8);
  }

  const float cexp = 0.08838834764831845f * LOG2E;
  bf16x8 ones;
#pragma unroll
  for (int i = 0; i < 8; i++) ones[i] = (bf16)1.0f;

#pragma unroll 1
  for (int pass = 0; pass < 2; pass++) {
    const int qb = (pass == 0) ? (31 - p) : p;
    const int q0 = qb * 64;
    const int nkt = qb + 1;

    const bf16* Qb = Q + ((size_t)(b * 16 + h) * 2048 + q0 + w * 16 + l15) * 128;
    bf16x8 aq[4];
#pragma unroll
    for (int kk = 0; kk < 4; kk++) aq[kk] = *(const bf16x8*)(Qb + kk * 32 + quad * 8);

    f32x4 o[9];
#pragma unroll
    for (int dt = 0; dt < 9; dt++) o[dt] = (f32x4)0.0f;

#pragma unroll 1
    for (int kt = 0; kt < nkt; kt++) {
      const int k0 = kt * 64;
      __syncthreads();
      {
        const size_t kbase = (size_t)k0 * 128;
#pragma unroll
        for (int i = 0; i < 4; i++) {
          const int c = w * 4 + i;
          async_cp16(Kb + kbase + okff[i], (char*)&Ks[0][0] + c * 1024);
          async_cp16(Vb + (size_t)k0 + ovff[i], (char*)&Vs[0][0] + c * 1024);
        }
      }
      __syncthreads();

      f32x4 s4[4];
#pragma unroll
      for (int j = 0; j < 4; j++) {
        f32x4 acc = (f32x4)0.0f;
        const int n = j * 16 + l15;
#pragma unroll
        for (int kk = 0; kk < 4; kk++) {
          bf16x8 bk = *(const bf16x8*)(
              &Ks[0][0] + n * 128 + (((kk * 4 + quad) ^ l15) * 8));
          acc = __builtin_amdgcn_mfma_f32_16x16x32_bf16(aq[kk], bk, acc, 0, 0, 0);
        }
        s4[j] = acc;
      }

      const bool diag = (kt == qb);
      const int qrow_base = q0 + w * 16 + quad * 4;
#pragma unroll
      for (int j = 0; j < 4; j++) {
        const int kg = k0 + j * 16 + l15;
#pragma unroll
        for (int r = 0; r < 4; r++) {
          float pv = EXP2F(s4[j][r] * cexp);
          if (diag && kg > qrow_base + r) pv = 0.0f;
          Ps[w][quad * 4 + r][j * 16 + l15] = (bf16)pv;
        }
      }
      __asm__ volatile("s_waitcnt lgkmcnt(0)" ::: "memory");

#pragma unroll
      for (int kk = 0; kk < 2; kk++) {
        bf16x8 pa = *(const bf16x8*)&Ps[w][l15][kk * 32 + quad * 8];
#pragma unroll
        for (int dt = 0; dt < 8; dt++) {
          const int d = dt * 16 + l15;
          bf16x8 vb = *(const bf16x8*)(
              &Vs[0][0] + d * 64 + (((kk * 4 + quad) ^ (d & 7)) * 8));
          o[dt] = __builtin_amdgcn_mfma_f32_16x16x32_bf16(pa, vb, o[dt], 0, 0, 0);
        }
        o[8] = __builtin_amdgcn_mfma_f32_16x16x32_bf16(pa, ones, o[8], 0, 0, 0);
      }
    }

    bf16* Ob = O + ((size_t)(b * 2048 + q0 + w * 16 + quad * 4)) * 2048 + h * 128;
#pragma unroll
    for (int r = 0; r < 4; r++) {
      const float rinv = 1.0f / o[8][r];
#pragma unroll
      for (int dt = 0; dt < 8; dt++)
        Ob[(size_t)r * 2048 + dt * 16 + l15] = (bf16)(o[dt][r] * rinv);
    }
  }
}

// ============================================================
// Launcher — fp32 in/out, bf16 compute. 5 kernel launches.
// ws layout (bytes), total 88080384:
//   xb    bf16[4096x2048] : 0        .. 16777216  (reused as At)
//   wqkvb bf16[3072x2048] : 16777216 .. 29360128
//   wob   bf16[2048x2048] : 29360128 .. 37748736
//   qkvb  bf16[4096x3072] : 37748736 .. 62914560
//   Qr    bf16[2,16,2048,128] : 62914560 .. 79691776
//   Kr    bf16[2, 4,2048,128] : 79691776 .. 83886080
//   Vt    bf16[2, 4,128,2048] : 83886080 .. 88080384
// ============================================================
extern "C" void kernel_launch(void* const* d_in, const int* in_sizes, int n_in,
                              void* d_out, int out_size, void* d_ws, size_t ws_size,
                              hipStream_t stream) {
  const float* x   = (const float*)d_in[0];
  const float* wq  = (const float*)d_in[1];
  const float* bq  = (const float*)d_in[2];
  const float* wk  = (const float*)d_in[3];
  const float* bk  = (const float*)d_in[4];
  const float* wv  = (const float*)d_in[5];
  const float* bv  = (const float*)d_in[6];
  const float* wo  = (const float*)d_in[7];
  const float* bo  = (const float*)d_in[8];
  const float* qg  = (const float*)d_in[9];
  const float* qbt = (const float*)d_in[10];
  const float* kg  = (const float*)d_in[11];
  const float* kbt = (const float*)d_in[12];
  float* out = (float*)d_out;

  char* ws = (char*)d_ws;
  if (ws_size < (size_t)88080384) return;
  bf16* xb    = (bf16*)(ws);
  bf16* wqkvb = (bf16*)(ws + 16777216);
  bf16* wob   = (bf16*)(ws + 29360128);
  bf16* qkvb  = (bf16*)(ws + 37748736);
  bf16* Qr    = (bf16*)(ws + 62914560);
  bf16* Kr    = (bf16*)(ws + 79691776);
  bf16* Vt    = (bf16*)(ws + 83886080);
  bf16* At    = (bf16*)(ws);  // aliases xb — x dead after QKV gemm

  cast_all<<<9216, 256, 0, stream>>>(x, wq, wk, wv, wo, xb, wqkvb, wob);
  gemm_bt<bf16, true, true><<<dim3(32, 24), 256, 0, stream>>>(
      xb, wqkvb, bq, bk, bv, qkvb, 4096, 3072, 2048);
  fused_mid<<<8448, 256, 0, stream>>>(qkvb, qg, qbt, kg, kbt, Qr, Kr, Vt);
  flash_attn<<<dim3(16, 16, 2), 256, 0, stream>>>(Qr, Kr, Vt, At);
  gemm_bt<float, false, false><<<dim3(32, 16), 256, 0, stream>>>(
      At, wob, bo, nullptr, nullptr, out, 4096, 2048, 2048);
}